// Round 2
// baseline (465.653 us; speedup 1.0000x reference)
//
#include <hip/hip_runtime.h>
#include <hip/hip_bf16.h>

typedef __hip_bfloat16 bf16;
typedef __hip_bfloat162 bf162;
typedef short v8s __attribute__((ext_vector_type(8)));
typedef float v4f __attribute__((ext_vector_type(4)));

// ---------------- index dtype detection ----------------
// int64 little-endian with values < 2^31: every odd int32 slot is a zero high
// word. Real int32 data: odd slots are node ids, nonzero w.h.p. (p_zero=1e-5).
// flag = 1 (int32 stride) or 2 (int64: value at logical j is slot 2j).
__global__ void detect_kernel(const int* __restrict__ e0, int* __restrict__ flag, int E) {
    __shared__ int sm;
    int t = threadIdx.x;
    if (t == 0) sm = 0;
    __syncthreads();
    int nz = 0;
    for (int i = t; i < 2048; i += 256) {
        int slot = 2 * i + 1;
        if (slot < 2 * E) nz |= (e0[slot] != 0);
    }
    if (nz) atomicOr(&sm, 1);
    __syncthreads();
    if (t == 0) *flag = sm ? 1 : 2;
}

// ---------------- CSR build ----------------

__global__ void hist_kernel(const int* __restrict__ e0, const int* __restrict__ e1,
                            const int* __restrict__ flag,
                            int* __restrict__ cnt, int E, int N) {
    int e = blockIdx.x * 256 + threadIdx.x;
    if (e >= 2 * E) return;
    int st = *flag;
    int r = e >= E;
    const int* ei = r ? e1 : e0;
    int idx = r ? e - E : e;
    int tgt = ei[(size_t)(E + idx) * st];     // row 1 of [2,E] = targets
    atomicAdd(&cnt[r * N + tgt], 1);
}

__global__ void scan_a_kernel(const int* __restrict__ cnt, int* __restrict__ bsum, int n) {
    __shared__ int sm[256];
    int t = threadIdx.x;
    int base = blockIdx.x * 1024 + t * 4;
    int s = 0;
#pragma unroll
    for (int j = 0; j < 4; ++j) { int i = base + j; s += (i < n) ? cnt[i] : 0; }
    sm[t] = s; __syncthreads();
    for (int d = 128; d > 0; d >>= 1) { if (t < d) sm[t] += sm[t + d]; __syncthreads(); }
    if (t == 0) bsum[blockIdx.x] = sm[0];
}

__global__ void scan_b_kernel(const int* __restrict__ bsum, int* __restrict__ boff, int nb) {
    __shared__ int sm[256];
    int t = threadIdx.x;
    int v = (t < nb) ? bsum[t] : 0;
    sm[t] = v; __syncthreads();
    for (int d = 1; d < 256; d <<= 1) {
        int add = (t >= d) ? sm[t - d] : 0;
        __syncthreads();
        sm[t] += add;
        __syncthreads();
    }
    boff[t] = sm[t] - v;   // exclusive
}

__global__ void scan_c_kernel(const int* __restrict__ cnt, const int* __restrict__ boff,
                              int* __restrict__ off, int* __restrict__ cur, int n) {
    __shared__ int sm[256];
    int t = threadIdx.x;
    int base = blockIdx.x * 1024 + t * 4;
    int v[4]; int s = 0;
#pragma unroll
    for (int j = 0; j < 4; ++j) { int i = base + j; v[j] = (i < n) ? cnt[i] : 0; s += v[j]; }
    sm[t] = s; __syncthreads();
    for (int d = 1; d < 256; d <<= 1) {
        int add = (t >= d) ? sm[t - d] : 0;
        __syncthreads();
        sm[t] += add;
        __syncthreads();
    }
    int run = sm[t] - s + boff[blockIdx.x];
#pragma unroll
    for (int j = 0; j < 4; ++j) {
        int i = base + j;
        if (i < n) { off[i] = run; cur[i] = run; }
        run += v[j];
    }
}

__global__ void fill_kernel(const int* __restrict__ e0, const int* __restrict__ e1,
                            const int* __restrict__ flag,
                            int* __restrict__ cur, int* __restrict__ esrc, int E, int N) {
    int e = blockIdx.x * 256 + threadIdx.x;
    if (e >= 2 * E) return;
    int st = *flag;
    int r = e >= E;
    const int* ei = r ? e1 : e0;
    int idx = r ? e - E : e;
    int src = ei[(size_t)idx * st];
    int tgt = ei[(size_t)(E + idx) * st];
    int pos = atomicAdd(&cur[r * N + tgt], 1);
    esrc[pos] = src;
}

// ---------------- gather-reduce: H[n][r*128 + c] = sum_{incoming} x[src][c] (fp32 acc -> bf16) ----------------

__global__ void gather_kernel(const float* __restrict__ x, const int* __restrict__ off,
                              const int* __restrict__ cnt, const int* __restrict__ esrc,
                              bf162* __restrict__ H2, int N) {
    int w = blockIdx.x * 4 + (threadIdx.x >> 6);   // one wave per (node, relation)
    int lane = threadIdx.x & 63;
    if (w >= 2 * N) return;
    int r = w >= N;
    int n = r ? w - N : w;
    int s0 = off[w], c = cnt[w];
    float ax = 0.f, ay = 0.f;
    const float2* x2 = (const float2*)x;
    for (int i = 0; i < c; ++i) {
        int s = esrc[s0 + i];
        float2 v = x2[(size_t)s * 64 + lane];
        ax += v.x;
        ay += v.y;
    }
    bf162 o; o.x = __float2bfloat16(ax); o.y = __float2bfloat16(ay);
    H2[(size_t)n * 128 + r * 64 + lane] = o;
}

// ---------------- weight prep (fp32 -> bf16): B1T[co][k] K=384, B2T[co][k], conv bias fp32 ----------------

__global__ void prep_kernel(const float* __restrict__ Wrel, const float* __restrict__ Wself,
                            const float* __restrict__ convw, const float* __restrict__ convb,
                            bf16* __restrict__ B1T, bf16* __restrict__ B2T, float* __restrict__ cbf) {
    int i = blockIdx.x * 256 + threadIdx.x;
    if (i < 49152) {
        int co = i / 384, k = i % 384;
        float v;
        if (k < 128)      v = Wrel[co * 128 + k];
        else if (k < 256) v = Wrel[16384 + co * 128 + (k - 128)];
        else              v = Wself[co * 128 + (k - 256)];
        B1T[i] = __float2bfloat16(v);
    } else if (i < 98304) {
        int j = i - 49152;
        int co = j / 384, k = j % 384, kk = k >> 7, ci = k & 127;
        B2T[j] = __float2bfloat16(convw[co * 384 + ci * 3 + kk]);
    } else if (i < 98432) {
        int c = i - 98304;
        cbf[c] = convb[c];
    }
}

// ---------------- GEMM1: agg[M,128](bf16) = [H | x] @ B1T^T,  K = 384 ----------------

__global__ __launch_bounds__(256) void gemm1_kernel(const bf16* __restrict__ H,
                                                    const float* __restrict__ x,
                                                    const bf16* __restrict__ B1T,
                                                    bf16* __restrict__ agg, int M) {
    __shared__ bf16 Al[128 * 72];
    __shared__ bf16 Bl[128 * 72];
    int t = threadIdx.x;
    int lane = t & 63, wv = t >> 6, wm = wv >> 1, wn = wv & 1;
    int m0 = blockIdx.x * 128;
    v4f acc[4][4] = {};
    for (int kt = 0; kt < 6; ++kt) {
        int k0 = kt * 64;
#pragma unroll
        for (int i = 0; i < 4; ++i) {
            int q = i * 256 + t;
            int row = q >> 3, ch = q & 7;
            int grow = m0 + row;
            if (k0 < 256) {
                int4 va = {0, 0, 0, 0};
                if (grow < M) va = *(const int4*)(H + (size_t)grow * 256 + k0 + ch * 8);
                *(int4*)&Al[row * 72 + ch * 8] = va;
            } else {
                union { int4 i4; bf16 h[8]; } u;
                float4 f0 = {0,0,0,0}, f1 = {0,0,0,0};
                if (grow < M) {
                    const float* src = x + (size_t)grow * 128 + (k0 - 256) + ch * 8;
                    f0 = *(const float4*)src;
                    f1 = *(const float4*)(src + 4);
                }
                u.h[0] = __float2bfloat16(f0.x); u.h[1] = __float2bfloat16(f0.y);
                u.h[2] = __float2bfloat16(f0.z); u.h[3] = __float2bfloat16(f0.w);
                u.h[4] = __float2bfloat16(f1.x); u.h[5] = __float2bfloat16(f1.y);
                u.h[6] = __float2bfloat16(f1.z); u.h[7] = __float2bfloat16(f1.w);
                *(int4*)&Al[row * 72 + ch * 8] = u.i4;
            }
            *(int4*)&Bl[row * 72 + ch * 8] = *(const int4*)(B1T + row * 384 + k0 + ch * 8);
        }
        __syncthreads();
        int r = lane & 15, qq = lane >> 4;
#pragma unroll
        for (int ks = 0; ks < 2; ++ks) {
            v8s af[4], bfr[4];
#pragma unroll
            for (int tm = 0; tm < 4; ++tm)
                af[tm] = *(const v8s*)&Al[(wm * 64 + tm * 16 + r) * 72 + ks * 32 + qq * 8];
#pragma unroll
            for (int tn = 0; tn < 4; ++tn)
                bfr[tn] = *(const v8s*)&Bl[(wn * 64 + tn * 16 + r) * 72 + ks * 32 + qq * 8];
#pragma unroll
            for (int tm = 0; tm < 4; ++tm)
#pragma unroll
                for (int tn = 0; tn < 4; ++tn)
                    acc[tm][tn] = __builtin_amdgcn_mfma_f32_16x16x32_bf16(af[tm], bfr[tn], acc[tm][tn], 0, 0, 0);
        }
        __syncthreads();
    }
    int r = lane & 15, qq = lane >> 4;
#pragma unroll
    for (int tm = 0; tm < 4; ++tm)
#pragma unroll
        for (int tn = 0; tn < 4; ++tn)
#pragma unroll
            for (int reg = 0; reg < 4; ++reg) {
                int grow = m0 + wm * 64 + tm * 16 + qq * 4 + reg;
                if (grow < M) {
                    int col = wn * 64 + tn * 16 + r;
                    agg[(size_t)grow * 128 + col] = __float2bfloat16(acc[tm][tn][reg]);
                }
            }
}

// ---------------- GEMM2: out[n](fp32) = relu(b + sum_kk agg[n+kk-1] @ Wkk^T),  K = 384 ----------------

__global__ __launch_bounds__(256) void gemm2_kernel(const bf16* __restrict__ agg,
                                                    const bf16* __restrict__ B2T,
                                                    const float* __restrict__ cbf,
                                                    float* __restrict__ out, int M) {
    __shared__ bf16 Al[128 * 72];
    __shared__ bf16 Bl[128 * 72];
    int t = threadIdx.x;
    int lane = t & 63, wv = t >> 6, wm = wv >> 1, wn = wv & 1;
    int m0 = blockIdx.x * 128;
    v4f acc[4][4] = {};
    for (int kt = 0; kt < 6; ++kt) {
        int k0 = kt * 64;
        int kk = k0 >> 7;          // which conv tap (0..2)
        int rem = k0 & 127;        // ci offset within tap
#pragma unroll
        for (int i = 0; i < 4; ++i) {
            int q = i * 256 + t;
            int row = q >> 3, ch = q & 7;
            int srow = m0 + row + kk - 1;
            int4 va = {0, 0, 0, 0};
            if (srow >= 0 && srow < M) {
                va = *(const int4*)(agg + (size_t)srow * 128 + rem + ch * 8);
            }
            *(int4*)&Al[row * 72 + ch * 8] = va;
            *(int4*)&Bl[row * 72 + ch * 8] = *(const int4*)(B2T + row * 384 + k0 + ch * 8);
        }
        __syncthreads();
        int r = lane & 15, qq = lane >> 4;
#pragma unroll
        for (int ks = 0; ks < 2; ++ks) {
            v8s af[4], bfr[4];
#pragma unroll
            for (int tm = 0; tm < 4; ++tm)
                af[tm] = *(const v8s*)&Al[(wm * 64 + tm * 16 + r) * 72 + ks * 32 + qq * 8];
#pragma unroll
            for (int tn = 0; tn < 4; ++tn)
                bfr[tn] = *(const v8s*)&Bl[(wn * 64 + tn * 16 + r) * 72 + ks * 32 + qq * 8];
#pragma unroll
            for (int tm = 0; tm < 4; ++tm)
#pragma unroll
                for (int tn = 0; tn < 4; ++tn)
                    acc[tm][tn] = __builtin_amdgcn_mfma_f32_16x16x32_bf16(af[tm], bfr[tn], acc[tm][tn], 0, 0, 0);
        }
        __syncthreads();
    }
    int r = lane & 15, qq = lane >> 4;
#pragma unroll
    for (int tm = 0; tm < 4; ++tm)
#pragma unroll
        for (int tn = 0; tn < 4; ++tn) {
            int col = wn * 64 + tn * 16 + r;
            float bias = cbf[col];
#pragma unroll
            for (int reg = 0; reg < 4; ++reg) {
                int grow = m0 + wm * 64 + tm * 16 + qq * 4 + reg;
                if (grow < M) {
                    float v = acc[tm][tn][reg] + bias;
                    out[(size_t)grow * 128 + col] = fmaxf(v, 0.f);
                }
            }
        }
}

// ---------------- launch ----------------

extern "C" void kernel_launch(void* const* d_in, const int* in_sizes, int n_in,
                              void* d_out, int out_size, void* d_ws, size_t ws_size,
                              hipStream_t stream) {
    const float* x     = (const float*)d_in[0];
    const int*   e0    = (const int*)d_in[1];
    const int*   e1    = (const int*)d_in[2];
    const float* Wrel  = (const float*)d_in[3];
    const float* Wself = (const float*)d_in[4];
    const float* convw = (const float*)d_in[5];
    const float* convb = (const float*)d_in[6];
    float* out = (float*)d_out;

    int N = in_sizes[0] / 128;   // 100000
    int E = in_sizes[1] / 2;     // 600000

    char* p = (char*)d_ws;
    auto alloc = [&](size_t bytes) { char* q = p; p += (bytes + 255) & ~(size_t)255; return q; };
    int*  cnt  = (int*)alloc((size_t)2 * N * 4);
    int*  off  = (int*)alloc((size_t)2 * N * 4);
    int*  cur  = (int*)alloc((size_t)2 * N * 4);
    int*  bsum = (int*)alloc(1024);
    int*  boff = (int*)alloc(1024);
    int*  flag = (int*)alloc(256);
    int*  esrc = (int*)alloc((size_t)2 * E * 4);
    bf16* H    = (bf16*)alloc((size_t)N * 256 * 2);
    bf16* agg  = (bf16*)alloc((size_t)N * 128 * 2);
    bf16* B1T  = (bf16*)alloc(384 * 128 * 2);
    bf16* B2T  = (bf16*)alloc(384 * 128 * 2);
    float* cbf = (float*)alloc(512);

    hipMemsetAsync(cnt, 0, (size_t)2 * N * 4, stream);

    detect_kernel<<<1, 256, 0, stream>>>(e0, flag, E);

    int edgeBlocks = (2 * E + 255) / 256;
    hist_kernel<<<edgeBlocks, 256, 0, stream>>>(e0, e1, flag, cnt, E, N);

    int NB = (2 * N + 1023) / 1024;
    scan_a_kernel<<<NB, 256, 0, stream>>>(cnt, bsum, 2 * N);
    scan_b_kernel<<<1, 256, 0, stream>>>(bsum, boff, NB);
    scan_c_kernel<<<NB, 256, 0, stream>>>(cnt, boff, off, cur, 2 * N);

    fill_kernel<<<edgeBlocks, 256, 0, stream>>>(e0, e1, flag, cur, esrc, E, N);

    gather_kernel<<<(2 * N + 3) / 4, 256, 0, stream>>>(x, off, cnt, esrc, (bf162*)H, N);

    prep_kernel<<<(98432 + 255) / 256, 256, 0, stream>>>(Wrel, Wself, convw, convb, B1T, B2T, cbf);

    int mBlocks = (N + 127) / 128;
    gemm1_kernel<<<mBlocks, 256, 0, stream>>>(H, x, B1T, agg, N);
    gemm2_kernel<<<mBlocks, 256, 0, stream>>>(agg, B2T, cbf, out, N);
}

// Round 3
// 378.369 us; speedup vs baseline: 1.2307x; 1.2307x over previous
//
#include <hip/hip_runtime.h>
#include <hip/hip_bf16.h>

typedef __hip_bfloat16 bf16;
typedef __hip_bfloat162 bf162;
typedef short v8s __attribute__((ext_vector_type(8)));
typedef float v4f __attribute__((ext_vector_type(4)));

#define BFLO(u) __uint_as_float((u) << 16)
#define BFHI(u) __uint_as_float((u) & 0xffff0000u)

// ---------------- index dtype detection ----------------
// int64 little-endian with values < 2^31: every odd int32 slot is a zero high
// word. Real int32 data: odd slots are node ids, nonzero w.h.p.
__global__ void detect_kernel(const int* __restrict__ e0, int* __restrict__ flag, int E) {
    __shared__ int sm;
    int t = threadIdx.x;
    if (t == 0) sm = 0;
    __syncthreads();
    int nz = 0;
    for (int i = t; i < 2048; i += 256) {
        int slot = 2 * i + 1;
        if (slot < 2 * E) nz |= (e0[slot] != 0);
    }
    if (nz) atomicOr(&sm, 1);
    __syncthreads();
    if (t == 0) *flag = sm ? 1 : 2;
}

// ---------------- x (fp32) -> Abig cols 256:383 (bf16) ----------------
// Abig row = 384 bf16 = 96 uint2. x portion starts at uint2 index 64.
__global__ void cvt_kernel(const float4* __restrict__ x4, uint2* __restrict__ Ab, int N) {
    int i = blockIdx.x * 256 + threadIdx.x;   // over N*32 groups of 4 floats
    if (i >= N * 32) return;
    int n = i >> 5, g = i & 31;
    float4 f = x4[i];
    union { uint2 u; bf16 h[4]; } o;
    o.h[0] = __float2bfloat16(f.x); o.h[1] = __float2bfloat16(f.y);
    o.h[2] = __float2bfloat16(f.z); o.h[3] = __float2bfloat16(f.w);
    Ab[(size_t)n * 96 + 64 + g] = o.u;
}

// ---------------- CSR build ----------------

__global__ void hist_kernel(const int* __restrict__ e0, const int* __restrict__ e1,
                            const int* __restrict__ flag,
                            int* __restrict__ cnt, int E, int N) {
    int e = blockIdx.x * 256 + threadIdx.x;
    if (e >= 2 * E) return;
    int st = *flag;
    int r = e >= E;
    const int* ei = r ? e1 : e0;
    int idx = r ? e - E : e;
    int tgt = ei[(size_t)(E + idx) * st];     // row 1 of [2,E] = targets
    atomicAdd(&cnt[r * N + tgt], 1);
}

__global__ void scan_a_kernel(const int* __restrict__ cnt, int* __restrict__ bsum, int n) {
    __shared__ int sm[256];
    int t = threadIdx.x;
    int base = blockIdx.x * 1024 + t * 4;
    int s = 0;
#pragma unroll
    for (int j = 0; j < 4; ++j) { int i = base + j; s += (i < n) ? cnt[i] : 0; }
    sm[t] = s; __syncthreads();
    for (int d = 128; d > 0; d >>= 1) { if (t < d) sm[t] += sm[t + d]; __syncthreads(); }
    if (t == 0) bsum[blockIdx.x] = sm[0];
}

__global__ void scan_b_kernel(const int* __restrict__ bsum, int* __restrict__ boff, int nb) {
    __shared__ int sm[256];
    int t = threadIdx.x;
    int v = (t < nb) ? bsum[t] : 0;
    sm[t] = v; __syncthreads();
    for (int d = 1; d < 256; d <<= 1) {
        int add = (t >= d) ? sm[t - d] : 0;
        __syncthreads();
        sm[t] += add;
        __syncthreads();
    }
    boff[t] = sm[t] - v;   // exclusive
}

__global__ void scan_c_kernel(const int* __restrict__ cnt, const int* __restrict__ boff,
                              int* __restrict__ off, int* __restrict__ cur, int n) {
    __shared__ int sm[256];
    int t = threadIdx.x;
    int base = blockIdx.x * 1024 + t * 4;
    int v[4]; int s = 0;
#pragma unroll
    for (int j = 0; j < 4; ++j) { int i = base + j; v[j] = (i < n) ? cnt[i] : 0; s += v[j]; }
    sm[t] = s; __syncthreads();
    for (int d = 1; d < 256; d <<= 1) {
        int add = (t >= d) ? sm[t - d] : 0;
        __syncthreads();
        sm[t] += add;
        __syncthreads();
    }
    int run = sm[t] - s + boff[blockIdx.x];
#pragma unroll
    for (int j = 0; j < 4; ++j) {
        int i = base + j;
        if (i < n) { off[i] = run; cur[i] = run; }
        run += v[j];
    }
}

__global__ void fill_kernel(const int* __restrict__ e0, const int* __restrict__ e1,
                            const int* __restrict__ flag,
                            int* __restrict__ cur, int* __restrict__ esrc, int E, int N) {
    int e = blockIdx.x * 256 + threadIdx.x;
    if (e >= 2 * E) return;
    int st = *flag;
    int r = e >= E;
    const int* ei = r ? e1 : e0;
    int idx = r ? e - E : e;
    int src = ei[(size_t)idx * st];
    int tgt = ei[(size_t)(E + idx) * st];
    int pos = atomicAdd(&cur[r * N + tgt], 1);
    esrc[pos] = src;
}

// ---------------- gather-reduce into Abig cols 0:255 ----------------
// One half-wave (32 lanes x 8B = 256B = one bf16 row) per (node, relation).
// Edge loop unrolled x4 with clamped indices: duplicate tail loads hit the
// same L1-hot line (free) while keeping 4 row loads in flight (MLP).
__global__ __launch_bounds__(256) void gather_kernel(const int* __restrict__ off,
                                                     const int* __restrict__ cnt,
                                                     const int* __restrict__ esrc,
                                                     uint2* __restrict__ Ab, int N) {
    int hw = blockIdx.x * 8 + (threadIdx.x >> 5);
    int lane = threadIdx.x & 31;
    if (hw >= 2 * N) return;
    int r = (hw >= N);
    int n = r ? hw - N : hw;
    int s0 = off[hw], c = cnt[hw];
    float a0 = 0.f, a1 = 0.f, a2 = 0.f, a3 = 0.f;
    for (int i = 0; i < c; i += 4) {
        int cm1 = c - 1;
        int j1 = (i + 1 <= cm1) ? i + 1 : cm1;
        int j2 = (i + 2 <= cm1) ? i + 2 : cm1;
        int j3 = (i + 3 <= cm1) ? i + 3 : cm1;
        int sA = esrc[s0 + i];
        int sB = esrc[s0 + j1];
        int sC = esrc[s0 + j2];
        int sD = esrc[s0 + j3];
        uint2 vA = Ab[(size_t)sA * 96 + 64 + lane];
        uint2 vB = Ab[(size_t)sB * 96 + 64 + lane];
        uint2 vC = Ab[(size_t)sC * 96 + 64 + lane];
        uint2 vD = Ab[(size_t)sD * 96 + 64 + lane];
        a0 += BFLO(vA.x); a1 += BFHI(vA.x); a2 += BFLO(vA.y); a3 += BFHI(vA.y);
        if (i + 1 < c) { a0 += BFLO(vB.x); a1 += BFHI(vB.x); a2 += BFLO(vB.y); a3 += BFHI(vB.y); }
        if (i + 2 < c) { a0 += BFLO(vC.x); a1 += BFHI(vC.x); a2 += BFLO(vC.y); a3 += BFHI(vC.y); }
        if (i + 3 < c) { a0 += BFLO(vD.x); a1 += BFHI(vD.x); a2 += BFLO(vD.y); a3 += BFHI(vD.y); }
    }
    union { uint2 u; bf16 h[4]; } o;
    o.h[0] = __float2bfloat16(a0); o.h[1] = __float2bfloat16(a1);
    o.h[2] = __float2bfloat16(a2); o.h[3] = __float2bfloat16(a3);
    Ab[(size_t)n * 96 + (size_t)r * 32 + lane] = o.u;
}

// ---------------- weight prep (fp32 -> bf16) ----------------

__global__ void prep_kernel(const float* __restrict__ Wrel, const float* __restrict__ Wself,
                            const float* __restrict__ convw, const float* __restrict__ convb,
                            bf16* __restrict__ B1T, bf16* __restrict__ B2T, float* __restrict__ cbf) {
    int i = blockIdx.x * 256 + threadIdx.x;
    if (i < 49152) {
        int co = i / 384, k = i % 384;
        float v;
        if (k < 128)      v = Wrel[co * 128 + k];
        else if (k < 256) v = Wrel[16384 + co * 128 + (k - 128)];
        else              v = Wself[co * 128 + (k - 256)];
        B1T[i] = __float2bfloat16(v);
    } else if (i < 98304) {
        int j = i - 49152;
        int co = j / 384, k = j % 384, kk = k >> 7, ci = k & 127;
        B2T[j] = __float2bfloat16(convw[co * 384 + ci * 3 + kk]);
    } else if (i < 98432) {
        int c = i - 98304;
        cbf[c] = convb[c];
    }
}

// ---------------- GEMM1: agg[M,128](bf16) = Abig @ B1T^T,  K = 384 ----------------

__global__ __launch_bounds__(256) void gemm1_kernel(const bf16* __restrict__ Ab,
                                                    const bf16* __restrict__ B1T,
                                                    bf16* __restrict__ agg, int M) {
    __shared__ bf16 Al[128 * 72];
    __shared__ bf16 Bl[128 * 72];
    int t = threadIdx.x;
    int lane = t & 63, wv = t >> 6, wm = wv >> 1, wn = wv & 1;
    int m0 = blockIdx.x * 128;
    v4f acc[4][4] = {};
    for (int kt = 0; kt < 6; ++kt) {
        int k0 = kt * 64;
#pragma unroll
        for (int i = 0; i < 4; ++i) {
            int q = i * 256 + t;
            int row = q >> 3, ch = q & 7;
            int grow = m0 + row;
            int4 va = {0, 0, 0, 0};
            if (grow < M) va = *(const int4*)(Ab + (size_t)grow * 384 + k0 + ch * 8);
            *(int4*)&Al[row * 72 + ch * 8] = va;
            *(int4*)&Bl[row * 72 + ch * 8] = *(const int4*)(B1T + row * 384 + k0 + ch * 8);
        }
        __syncthreads();
        int r = lane & 15, qq = lane >> 4;
#pragma unroll
        for (int ks = 0; ks < 2; ++ks) {
            v8s af[4], bfr[4];
#pragma unroll
            for (int tm = 0; tm < 4; ++tm)
                af[tm] = *(const v8s*)&Al[(wm * 64 + tm * 16 + r) * 72 + ks * 32 + qq * 8];
#pragma unroll
            for (int tn = 0; tn < 4; ++tn)
                bfr[tn] = *(const v8s*)&Bl[(wn * 64 + tn * 16 + r) * 72 + ks * 32 + qq * 8];
#pragma unroll
            for (int tm = 0; tm < 4; ++tm)
#pragma unroll
                for (int tn = 0; tn < 4; ++tn)
                    acc[tm][tn] = __builtin_amdgcn_mfma_f32_16x16x32_bf16(af[tm], bfr[tn], acc[tm][tn], 0, 0, 0);
        }
        __syncthreads();
    }
    int r = lane & 15, qq = lane >> 4;
#pragma unroll
    for (int tm = 0; tm < 4; ++tm)
#pragma unroll
        for (int tn = 0; tn < 4; ++tn)
#pragma unroll
            for (int reg = 0; reg < 4; ++reg) {
                int grow = m0 + wm * 64 + tm * 16 + qq * 4 + reg;
                if (grow < M) {
                    int col = wn * 64 + tn * 16 + r;
                    agg[(size_t)grow * 128 + col] = __float2bfloat16(acc[tm][tn][reg]);
                }
            }
}

// ---------------- GEMM2: out[n](fp32) = relu(b + sum_kk agg[n+kk-1] @ Wkk^T),  K = 384 ----------------

__global__ __launch_bounds__(256) void gemm2_kernel(const bf16* __restrict__ agg,
                                                    const bf16* __restrict__ B2T,
                                                    const float* __restrict__ cbf,
                                                    float* __restrict__ out, int M) {
    __shared__ bf16 Al[128 * 72];
    __shared__ bf16 Bl[128 * 72];
    int t = threadIdx.x;
    int lane = t & 63, wv = t >> 6, wm = wv >> 1, wn = wv & 1;
    int m0 = blockIdx.x * 128;
    v4f acc[4][4] = {};
    for (int kt = 0; kt < 6; ++kt) {
        int k0 = kt * 64;
        int kk = k0 >> 7;          // which conv tap (0..2)
        int rem = k0 & 127;        // ci offset within tap
#pragma unroll
        for (int i = 0; i < 4; ++i) {
            int q = i * 256 + t;
            int row = q >> 3, ch = q & 7;
            int srow = m0 + row + kk - 1;
            int4 va = {0, 0, 0, 0};
            if (srow >= 0 && srow < M) {
                va = *(const int4*)(agg + (size_t)srow * 128 + rem + ch * 8);
            }
            *(int4*)&Al[row * 72 + ch * 8] = va;
            *(int4*)&Bl[row * 72 + ch * 8] = *(const int4*)(B2T + row * 384 + k0 + ch * 8);
        }
        __syncthreads();
        int r = lane & 15, qq = lane >> 4;
#pragma unroll
        for (int ks = 0; ks < 2; ++ks) {
            v8s af[4], bfr[4];
#pragma unroll
            for (int tm = 0; tm < 4; ++tm)
                af[tm] = *(const v8s*)&Al[(wm * 64 + tm * 16 + r) * 72 + ks * 32 + qq * 8];
#pragma unroll
            for (int tn = 0; tn < 4; ++tn)
                bfr[tn] = *(const v8s*)&Bl[(wn * 64 + tn * 16 + r) * 72 + ks * 32 + qq * 8];
#pragma unroll
            for (int tm = 0; tm < 4; ++tm)
#pragma unroll
                for (int tn = 0; tn < 4; ++tn)
                    acc[tm][tn] = __builtin_amdgcn_mfma_f32_16x16x32_bf16(af[tm], bfr[tn], acc[tm][tn], 0, 0, 0);
        }
        __syncthreads();
    }
    int r = lane & 15, qq = lane >> 4;
#pragma unroll
    for (int tm = 0; tm < 4; ++tm)
#pragma unroll
        for (int tn = 0; tn < 4; ++tn) {
            int col = wn * 64 + tn * 16 + r;
            float bias = cbf[col];
#pragma unroll
            for (int reg = 0; reg < 4; ++reg) {
                int grow = m0 + wm * 64 + tm * 16 + qq * 4 + reg;
                if (grow < M) {
                    float v = acc[tm][tn][reg] + bias;
                    out[(size_t)grow * 128 + col] = fmaxf(v, 0.f);
                }
            }
        }
}

// ---------------- launch ----------------

extern "C" void kernel_launch(void* const* d_in, const int* in_sizes, int n_in,
                              void* d_out, int out_size, void* d_ws, size_t ws_size,
                              hipStream_t stream) {
    const float* x     = (const float*)d_in[0];
    const int*   e0    = (const int*)d_in[1];
    const int*   e1    = (const int*)d_in[2];
    const float* Wrel  = (const float*)d_in[3];
    const float* Wself = (const float*)d_in[4];
    const float* convw = (const float*)d_in[5];
    const float* convb = (const float*)d_in[6];
    float* out = (float*)d_out;

    int N = in_sizes[0] / 128;   // 100000
    int E = in_sizes[1] / 2;     // 600000

    char* p = (char*)d_ws;
    auto alloc = [&](size_t bytes) { char* q = p; p += (bytes + 255) & ~(size_t)255; return q; };
    int*  cnt  = (int*)alloc((size_t)2 * N * 4);
    int*  off  = (int*)alloc((size_t)2 * N * 4);
    int*  cur  = (int*)alloc((size_t)2 * N * 4);
    int*  bsum = (int*)alloc(1024);
    int*  boff = (int*)alloc(1024);
    int*  flag = (int*)alloc(256);
    int*  esrc = (int*)alloc((size_t)2 * E * 4);
    bf16* Ab   = (bf16*)alloc((size_t)N * 384 * 2);   // [H0 | H1 | x_bf16]
    bf16* agg  = (bf16*)alloc((size_t)N * 128 * 2);
    bf16* B1T  = (bf16*)alloc(384 * 128 * 2);
    bf16* B2T  = (bf16*)alloc(384 * 128 * 2);
    float* cbf = (float*)alloc(512);

    hipMemsetAsync(cnt, 0, (size_t)2 * N * 4, stream);

    detect_kernel<<<1, 256, 0, stream>>>(e0, flag, E);

    cvt_kernel<<<(N * 32 + 255) / 256, 256, 0, stream>>>((const float4*)x, (uint2*)Ab, N);

    int edgeBlocks = (2 * E + 255) / 256;
    hist_kernel<<<edgeBlocks, 256, 0, stream>>>(e0, e1, flag, cnt, E, N);

    int NB = (2 * N + 1023) / 1024;
    scan_a_kernel<<<NB, 256, 0, stream>>>(cnt, bsum, 2 * N);
    scan_b_kernel<<<1, 256, 0, stream>>>(bsum, boff, NB);
    scan_c_kernel<<<NB, 256, 0, stream>>>(cnt, boff, off, cur, 2 * N);

    fill_kernel<<<edgeBlocks, 256, 0, stream>>>(e0, e1, flag, cur, esrc, E, N);

    gather_kernel<<<(2 * N + 7) / 8, 256, 0, stream>>>(off, cnt, esrc, (uint2*)Ab, N);

    prep_kernel<<<(98432 + 255) / 256, 256, 0, stream>>>(Wrel, Wself, convw, convb, B1T, B2T, cbf);

    int mBlocks = (N + 127) / 128;
    gemm1_kernel<<<mBlocks, 256, 0, stream>>>(Ab, B1T, agg, N);
    gemm2_kernel<<<mBlocks, 256, 0, stream>>>(agg, B2T, cbf, out, N);
}